// Round 12
// baseline (1208.768 us; speedup 1.0000x reference)
//
#include <hip/hip_runtime.h>

#define NN 1024
#define BT 32
#define TT 32
#define NTILES ((TT * (TT + 1)) / 2)   // 528

// ---------------------------------------------------------------------------
// Fence-free cross-XCD protocol (batched sc0sc1 MALL ops). Round-12:
// phaseB runs TWO diagonals per barrier (32 intervals instead of 63).
// Register chains deepened to p1/p2/p3 on both term families:
//   kk=r,r+1,r+2 -> shfl_down(p1,2)/(p2,4)/(p3,6)  (ar1/ar2 static A-side)
//   m=c-1,c-2,c-3 -> p1 / p2+DJJc[c][c-1] / p3+DJJc[c][c-2]
// so wave-partials only touch Vtc rows >= r+4 (written >=1 barrier before
// their computing interval) and slice8 entries >=3 diags old (same-wave
// registers, tails precede partials). Prt slots rotate mod 4: write at
// interval floor(s/2)-1, read at floor(s/2), rewrite at floor(s/2)+1 --
// each pair barrier-separated. Exact term set preserved (duplicates are
// fmax-idempotent; stale-0 entries dominated by interval monotonicity).
// Traceback: round-9 parallel queue (verified).
// ---------------------------------------------------------------------------
__device__ __forceinline__ double gload_cc(const double* p) {
    double v;
    asm volatile("global_load_dwordx2 %0, %1, off sc0 sc1" : "=v"(v) : "v"(p));
    return v;
}
__device__ __forceinline__ void gstore_cc(double* p, double v) {
    asm volatile("global_store_dwordx2 %0, %1, off sc0 sc1" :: "v"(p), "v"(v));
}
__device__ __forceinline__ void gstore_flag(int* p, int v) {
    asm volatile("global_store_dword %0, %1, off sc0 sc1" :: "v"(p), "v"(v));
}
#define VWAIT0 asm volatile("s_waitcnt vmcnt(0)" ::: "memory")

__device__ __forceinline__ void waitflag2(const int* f, int a0, int b0, int a1, int b1) {
    const int* p0 = &f[(a0 * TT + b0) << 4];
    const int* p1 = &f[(a1 * TT + b1) << 4];
    int it = 0;
    while (true) {
        int v0, v1;
        asm volatile("global_load_dword %0, %2, off sc0 sc1\n\t"
                     "global_load_dword %1, %3, off sc0 sc1\n\t"
                     "s_waitcnt vmcnt(0)"
                     : "=&v"(v0), "=&v"(v1)
                     : "v"(p0), "v"(p1));
        if (v0 & v1) break;
        if (it < 8) __builtin_amdgcn_s_sleep(1);
        else        __builtin_amdgcn_s_sleep(15);
        ++it;
    }
    asm volatile("" ::: "memory");
}
__device__ __forceinline__ void waitflag4(const int* f, int a0, int b0, int a1, int b1,
                                          int a2, int b2, int a3, int b3) {
    const int* p0 = &f[(a0 * TT + b0) << 4];
    const int* p1 = &f[(a1 * TT + b1) << 4];
    const int* p2 = &f[(a2 * TT + b2) << 4];
    const int* p3 = &f[(a3 * TT + b3) << 4];
    int it = 0;
    while (true) {
        int v0, v1, v2, v3;
        asm volatile("global_load_dword %0, %4, off sc0 sc1\n\t"
                     "global_load_dword %1, %5, off sc0 sc1\n\t"
                     "global_load_dword %2, %6, off sc0 sc1\n\t"
                     "global_load_dword %3, %7, off sc0 sc1\n\t"
                     "s_waitcnt vmcnt(0)"
                     : "=&v"(v0), "=&v"(v1), "=&v"(v2), "=&v"(v3)
                     : "v"(p0), "v"(p1), "v"(p2), "v"(p3));
        if (v0 & v1 & v2 & v3) break;
        if (it < 8) __builtin_amdgcn_s_sleep(1);
        else        __builtin_amdgcn_s_sleep(15);
        ++it;
    }
    asm volatile("" ::: "memory");
}
__device__ __forceinline__ void waitflag2_blk(const int* f, int a0, int b0, int a1, int b1) {
    if (threadIdx.x < 64) waitflag2(f, a0, b0, a1, b1);
    __syncthreads();
}
__device__ __forceinline__ void waitflag4_blk(const int* f, int a0, int b0, int a1, int b1,
                                              int a2, int b2, int a3, int b3) {
    if (threadIdx.x < 64) waitflag4(f, a0, b0, a1, b1, a2, b2, a3, b3);
    __syncthreads();
}

// ---------------------------------------------------------------------------
__global__ void primes_kernel(const float* __restrict__ feat, int* __restrict__ primes) {
    int i = blockIdx.x * blockDim.x + threadIdx.x;
    if (i < NN) {
        float best = feat[i * NN];
        int arg = 0;
        for (int ch = 1; ch < 4; ++ch) {
            float v = feat[ch * NN * NN + i * NN];
            if (v > best) { best = v; arg = ch; }
        }
        const int P[4] = {2, 3, 5, 7};
        primes[i] = P[arg];
    }
}

__global__ void prep_kernel(const float* __restrict__ con, const int* __restrict__ primes,
                            float* __restrict__ S, double* __restrict__ R,
                            double* __restrict__ C, float* __restrict__ out,
                            int* __restrict__ flags,
                            int* __restrict__ qi, int* __restrict__ qj,
                            int* __restrict__ qready, int* __restrict__ qctl) {
    int idx = blockIdx.x * blockDim.x + threadIdx.x;
    int i = idx >> 10;
    int j = idx & (NN - 1);
    float c = (con[idx] + con[j * NN + i]) * 0.5f;
    int prod = primes[i] * primes[j];
    bool canon = (prod == 14) | (prod == 15) | (prod == 35);
    int d = i - j; if (d < 0) d = -d;
    S[idx] = (canon && d >= 4) ? c : 0.0f;
    R[idx] = 0.0;
    C[idx] = 0.0;
    out[idx] = 0.0f;
    if (idx < TT * TT * 16) flags[idx] = 0;
    if (idx < 4096) qready[idx] = (idx == 0) ? 1 : 0;
    if (idx == 0) {
        qi[0] = 0; qj[0] = NN - 1;
        qctl[0] = 0;      // head
        qctl[16] = 1;     // tail
        qctl[32] = 1;     // pending
    }
}

// ---------------------------------------------------------------------------
// Dataflow DP, 4 waves per 32x32 tile. Exactness: every candidate is one
// fp64 add of stored values; extra candidates are dominated (-1e30+x<0<=dp,
// stale-0 + V(sub) <= dp by interval monotonicity); fmax is exact => bitwise
// == numpy. phaseB term routing per cell (r,c) at diag s:
//   kk=r   -> shfl(p1,2)  (r==31: edge row)
//   kk=r+1 -> ar1+shfl(p2,4)  (r==30: edge; r==31: none)
//   kk=r+2 -> ar2+shfl(p3,6)  (r==29: edge; r>=30: none)
//   kk>=r+3 -> wave partial (Vtc rows >= r+4, diag <= s-4)
//   m=c-1 -> p1;  m=c-2 -> p2+DJJc[c][c-1];  m=c-3 -> p3+DJJc[c][c-2]
//   m<=c-4 (and stale-dominated/duplicate others) -> wave partial
// Partials for diags {2k,2k+1} computed in interval k-1; Prt mod-4 slots
// give every LDS write/read pair >=1 barrier separation (audited).
// ---------------------------------------------------------------------------
__global__ __launch_bounds__(256) void nuss_tiles_kernel(double* __restrict__ R,
                                                         double* __restrict__ C,
                                                         const float* __restrict__ S,
                                                         int* __restrict__ flags) {
    __shared__ double DJJc[32][33];
    __shared__ double Vtc[32][33];
    __shared__ __attribute__((aligned(16))) double Ast[32][34];
    __shared__ __attribute__((aligned(16))) double Bst[32][34];
    __shared__ double Pld[32][33];
    __shared__ float  Sld[32][32];
    __shared__ double edgeCol[33];
    __shared__ __attribute__((aligned(16))) double Prt[4][32][6];  // partial rotation

    int b = blockIdx.x, dd = 0;
    while (b >= TT - dd) { b -= TT - dd; ++dd; }
    const int I = b, J = b + dd;
    const int aI = I * BT, aJ = J * BT;
    const int tid = threadIdx.x;
    const int wid = tid >> 6;
    const int lane = tid & 63;
    const int r = lane >> 1;
    const int h = lane & 1;

    if (dd == 0) {
        #pragma unroll
        for (int w = 0; w < 4; ++w) {
            int idx = w * 256 + tid; int rr = idx >> 5, cc = idx & 31;
            Sld[rr][cc] = S[(aI + rr) * NN + aI + cc];
        }
        for (int idx = tid; idx < 32 * 33; idx += 256)
            ((double*)Vtc)[idx] = 0.0;
        __syncthreads();
        if (wid == 0) {
            double vrow[16];
            #pragma unroll
            for (int u = 0; u < 16; ++u) vrow[u] = 0.0;
            for (int s = 1; s <= 31; ++s) {
                int c = r + s;
                bool act = (c <= 31);
                double acc = 0.0;
                if (act) {
                    double t0 = 0.0, t1 = 0.0, t2 = 0.0, t3 = 0.0;
                    #pragma unroll
                    for (int u = 0; u < 16; u += 4) {
                        int k0 = h * 16 + u;
                        t0 = fmax(t0, vrow[u]     + Vtc[c][k0 + 1]);
                        t1 = fmax(t1, vrow[u + 1] + Vtc[c][k0 + 2]);
                        t2 = fmax(t2, vrow[u + 2] + Vtc[c][k0 + 3]);
                        t3 = fmax(t3, vrow[u + 3] + Vtc[c][k0 + 4]);
                    }
                    acc = fmax(fmax(t0, t1), fmax(t2, t3));
                }
                acc = fmax(acc, __shfl_xor(acc, 1));
                if (act) {
                    double best = fmax(acc, Vtc[c - 1][r + 1] + (double)Sld[r][c]);
                    if (h == 0) Vtc[c][r] = best;
                    #pragma unroll
                    for (int u = 0; u < 16; ++u)
                        if (h * 16 + u == c) vrow[u] = best;
                }
            }
        }
        __syncthreads();
        #pragma unroll
        for (int w = 0; w < 4; ++w) {
            int idx = w * 256 + tid; int rr = idx >> 5, cc = idx & 31;
            gstore_cc(&R[(aI + rr) * NN + aI + cc], Vtc[cc][rr]);
        }
        #pragma unroll
        for (int w = 0; w < 4; ++w) {
            int idx = w * 256 + tid; int cc = idx >> 5, rr = idx & 31;
            gstore_cc(&C[(aI + cc) * NN + aI + rr], Vtc[cc][rr]);
        }
        VWAIT0;
        __syncthreads();
        if (tid == 0) gstore_flag(&flags[(I * TT + I) << 4], 1);
        return;
    }

    // ---------------- off-diagonal tile ----------------
    const int nk = dd - 1;
    const int off = (wid & 1) * 16 + h * 8;          // this lane's 8-term slice
    waitflag2_blk(flags, I, I, J, J);

    double ra[4], rb[4];
    double ec = 0.0, ve = 0.0;
    double asl[8];
    double ar1 = 0.0, ar2 = 0.0;
    #pragma unroll
    for (int w = 0; w < 4; ++w) {
        int idx = w * 256 + tid; int cc = idx >> 5, mm = idx & 31;
        ra[w] = gload_cc(&C[(aJ + cc) * NN + aJ + mm]);
    }
    if (wid < 2) {
        #pragma unroll
        for (int u = 0; u < 8; ++u)
            asl[u] = gload_cc(&R[(aI + r) * NN + aI + off + u]);
    }
    if (r < 31) ar1 = gload_cc(&R[(aI + r) * NN + aI + r + 1]);
    if (r < 30) ar2 = gload_cc(&R[(aI + r) * NN + aI + r + 2]);
    if (wid == 0 && nk == 0) {
        if (lane < 33) ec = gload_cc(&R[(aI + lane) * NN + (aJ - 1)]);
        if (lane < 32) ve = gload_cc(&R[(aI + 32) * NN + aJ + lane]);
    }
    #pragma unroll
    for (int w = 0; w < 4; ++w) {
        int idx = w * 256 + tid; int rr = idx >> 5, cc = idx & 31;
        Sld[rr][cc] = S[(aI + rr) * NN + aJ + cc];
    }
    for (int idx = tid; idx < 32 * 33; idx += 256)
        ((double*)Vtc)[idx] = 0.0;
    VWAIT0;
    #pragma unroll
    for (int w = 0; w < 4; ++w) {
        int idx = w * 256 + tid; int cc = idx >> 5, mm = idx & 31;
        DJJc[cc][mm] = ra[w];
    }
    if (tid < 32) DJJc[tid][32] = 0.0;
    // slice8: aslice (waves 0,1; guard kk>r+2) or vrow (waves 2,3; init 0)
    double slice8[8];
    if (wid < 2) {
        #pragma unroll
        for (int u = 0; u < 8; ++u)
            slice8[u] = (off + u > r + 2) ? asl[u] : -1.0e30;
    } else {
        #pragma unroll
        for (int u = 0; u < 8; ++u) slice8[u] = 0.0;
    }
    if (wid == 0 && nk == 0) {
        if (lane < 33) edgeCol[lane] = ec;
        if (lane < 32) Vtc[lane][32] = ve;
    }
    __syncthreads();

    // ---- phaseA: all-wave cooperative, middle-out, readiness pairs ----
    double P[16];
    #pragma unroll
    for (int x = 0; x < 16; ++x) P[x] = 0.0;
    const int rg = lane >> 3, cg = lane & 7;
    const int r4 = rg * 4, c4 = cg * 4;

    auto kkloop = [&]() {
        for (int kk = wid * 8; kk < wid * 8 + 8; ++kk) {
            double2 av0 = *(const double2*)&Ast[kk][r4];
            double2 av1 = *(const double2*)&Ast[kk][r4 + 2];
            double2 bv0 = *(const double2*)&Bst[kk][c4];
            double2 bv1 = *(const double2*)&Bst[kk][c4 + 2];
            P[0]  = fmax(P[0],  av0.x + bv0.x); P[1]  = fmax(P[1],  av0.x + bv0.y);
            P[2]  = fmax(P[2],  av0.x + bv1.x); P[3]  = fmax(P[3],  av0.x + bv1.y);
            P[4]  = fmax(P[4],  av0.y + bv0.x); P[5]  = fmax(P[5],  av0.y + bv0.y);
            P[6]  = fmax(P[6],  av0.y + bv1.x); P[7]  = fmax(P[7],  av0.y + bv1.y);
            P[8]  = fmax(P[8],  av1.x + bv0.x); P[9]  = fmax(P[9],  av1.x + bv0.y);
            P[10] = fmax(P[10], av1.x + bv1.x); P[11] = fmax(P[11], av1.x + bv1.y);
            P[12] = fmax(P[12], av1.y + bv0.x); P[13] = fmax(P[13], av1.y + bv0.y);
            P[14] = fmax(P[14], av1.y + bv1.x); P[15] = fmax(P[15], av1.y + bv1.y);
        }
    };
    auto proc = [&](int t1, int t2, bool last) {
        if (t2 >= 0) waitflag4_blk(flags, I, t1, t1, J, I, t2, t2, J);
        else         waitflag2_blk(flags, I, t1, t1, J);
        if (last && wid == 0) {
            if (lane < 33) ec = gload_cc(&R[(aI + lane) * NN + (aJ - 1)]);
            if (lane < 32) ve = gload_cc(&R[(aI + 32) * NN + aJ + lane]);
        }
        int k1 = t1 * BT;
        #pragma unroll
        for (int w = 0; w < 4; ++w) {
            int idx = w * 256 + tid; int rr = idx >> 5, kk = idx & 31;
            ra[w] = gload_cc(&R[(aI + rr) * NN + k1 + kk]);
            rb[w] = gload_cc(&C[(aJ + rr) * NN + k1 + 1 + kk]);
        }
        VWAIT0;
        #pragma unroll
        for (int w = 0; w < 4; ++w) {
            int idx = w * 256 + tid; int rr = idx >> 5, kk = idx & 31;
            Ast[kk][rr] = ra[w];
            Bst[kk][rr] = rb[w];
        }
        if (last && wid == 0) {
            if (lane < 33) edgeCol[lane] = ec;
            if (lane < 32) Vtc[lane][32] = ve;
        }
        __syncthreads();
        if (t2 >= 0) {
            int k2 = t2 * BT;
            #pragma unroll
            for (int w = 0; w < 4; ++w) {
                int idx = w * 256 + tid; int rr = idx >> 5, kk = idx & 31;
                ra[w] = gload_cc(&R[(aI + rr) * NN + k2 + kk]);
                rb[w] = gload_cc(&C[(aJ + rr) * NN + k2 + 1 + kk]);
            }
        }
        kkloop();
        if (t2 >= 0) {
            __syncthreads();
            VWAIT0;
            #pragma unroll
            for (int w = 0; w < 4; ++w) {
                int idx = w * 256 + tid; int rr = idx >> 5, kk = idx & 31;
                Ast[kk][rr] = ra[w];
                Bst[kk][rr] = rb[w];
            }
            __syncthreads();
            kkloop();
        }
        __syncthreads();
    };

    {
        int tl = (I + J) >> 1, tr = ((I + J) >> 1) + 1;
        int pend = -1;
        for (int q = 0; q < nk; ++q) {
            int t;
            if ((q & 1) == 0) { if (tl >= I + 1) t = tl--; else t = tr++; }
            else              { if (tr <= J - 1) t = tr++; else t = tl--; }
            if (pend < 0) { pend = t; continue; }
            int rp = (pend - I > J - pend) ? pend - I : J - pend;
            int rt = (t - I > J - t) ? t - I : J - t;
            if (rp == rt) { proc(pend, t, q == nk - 1); pend = -1; }
            else          { proc(pend, -1, false); pend = t; }
        }
        if (pend >= 0) proc(pend, -1, true);
    }

    // ---- Pld merge (exact fmax, fixed barrier order) ----
    if (nk > 0) {
        if (wid == 0) {
            #pragma unroll
            for (int x = 0; x < 4; ++x)
                #pragma unroll
                for (int y = 0; y < 4; ++y)
                    Pld[r4 + x][c4 + y] = P[x * 4 + y];
        }
        __syncthreads();
        if (wid == 1) {
            #pragma unroll
            for (int x = 0; x < 4; ++x)
                #pragma unroll
                for (int y = 0; y < 4; ++y)
                    Pld[r4 + x][c4 + y] = fmax(Pld[r4 + x][c4 + y], P[x * 4 + y]);
        }
        __syncthreads();
        if (wid == 2) {
            #pragma unroll
            for (int x = 0; x < 4; ++x)
                #pragma unroll
                for (int y = 0; y < 4; ++y)
                    Pld[r4 + x][c4 + y] = fmax(Pld[r4 + x][c4 + y], P[x * 4 + y]);
        }
        __syncthreads();
        if (wid == 3) {
            #pragma unroll
            for (int x = 0; x < 4; ++x)
                #pragma unroll
                for (int y = 0; y < 4; ++y)
                    Pld[r4 + x][c4 + y] = fmax(Pld[r4 + x][c4 + y], P[x * 4 + y]);
        }
        __syncthreads();
    } else {
        for (int idx = tid; idx < 32 * 33; idx += 256)
            ((double*)Pld)[idx] = 0.0;
        __syncthreads();
    }

    // ---- phaseB: 4-wave k-split, off-chain partials, 1 barrier / 2 diags ----
    {
        const double* bsel = (wid < 2) ? &Vtc[0][0] : &DJJc[0][0];
        double ecr = edgeCol[r];
        double ecp = edgeCol[r + 1];
        double pv[8];
        double p1 = 0.0, p2 = 0.0, p3 = 0.0;
        double shc = 0.0, shp = 0.0, erc = 0.0, erp = 0.0;

#define PREFQ(SS)                                                     \
    { int cq_ = (r + (SS) - 31) & 31;                                 \
      const double* bp_ = bsel + cq_ * 33 + off + 1;                  \
      _Pragma("unroll")                                               \
      for (int u = 0; u < 8; ++u) pv[u] = bp_[u]; }

#define PARTQ(SS)                                                     \
    { double t0_ = fmax(slice8[0] + pv[0], slice8[1] + pv[1]);        \
      double t1_ = fmax(slice8[2] + pv[2], slice8[3] + pv[3]);        \
      double t2_ = fmax(slice8[4] + pv[4], slice8[5] + pv[5]);        \
      double t3_ = fmax(slice8[6] + pv[6], slice8[7] + pv[7]);        \
      double pa_ = fmax(fmax(t0_, t1_), fmax(t2_, t3_));              \
      pa_ = fmax(pa_, __shfl_xor(pa_, 1));                            \
      if (h == 0) Prt[(SS) & 3][r][wid] = pa_; }

#define TAILB(SS)                                                     \
    { int c_ = r + (SS) - 31;                                         \
      bool act_ = ((unsigned)c_ < 32u);                               \
      int cc_ = c_ & 31;                                              \
      double a0_ = Prt[(SS) & 3][r][0];                               \
      double a1_ = Prt[(SS) & 3][r][1];                               \
      double a2_ = Prt[(SS) & 3][r][2];                               \
      double a3_ = Prt[(SS) & 3][r][3];                               \
      double er_  = Vtc[cc_][32];                                     \
      double dj0_ = DJJc[cc_][0];                                     \
      double dj1_ = DJJc[cc_][(cc_ > 0) ? cc_ - 1 : 0];               \
      double dj2_ = DJJc[cc_][(cc_ > 1) ? cc_ - 2 : 0];               \
      double pld_ = Pld[r][cc_];                                      \
      float  sld_ = Sld[r][cc_];                                      \
      shp = shc; erp = erc; erc = er_;                                \
      shc = __shfl_down(p1, 2);                                       \
      double shd_ = __shfl_down(p2, 4);                               \
      double she_ = __shfl_down(p3, 6);                               \
      double acc_ = fmax(fmax(a0_, a1_), fmax(a2_, a3_));             \
      if (act_) {                                                     \
          double b0_ = fmax(acc_, (r == 31) ? erc : shc);             \
          double b1_ = (r < 31) ? (ar1 + ((r == 30) ? erc : shd_))    \
                                : -1.0e30;                            \
          double b5_ = (r < 30) ? (ar2 + ((r == 29) ? erc : she_))    \
                                : -1.0e30;                            \
          double b2_ = fmax(p1, p2 + dj1_);                           \
          double b6_ = p3 + dj2_;                                     \
          double b3_ = fmax(ecr + dj0_, pld_);                        \
          double pvv_ = (c_ == 0) ? ecp : ((r == 31) ? erp : shp);    \
          double b4_ = fmax(pvv_ + (double)sld_, fmax(b1_, b5_));     \
          double best_ = fmax(fmax(b0_, fmax(b2_, b6_)),              \
                              fmax(b3_, b4_));                        \
          if (wid == 0 && h == 0) Vtc[c_][r] = best_;                 \
          if (wid >= 2) {                                             \
              _Pragma("unroll")                                       \
              for (int u = 0; u < 8; ++u)                             \
                  if (off + u == c_) slice8[u] = best_;               \
          }                                                           \
          p3 = p2; p2 = p1; p1 = best_;                               \
      } else { p3 = p2; p2 = p1; }                                    \
    }

        // prologue: partials for diags 0 and 1
        PREFQ(0) PARTQ(0)
        PREFQ(1) PARTQ(1)
        __syncthreads();
        for (int s2 = 0; s2 < 64; s2 += 2) {
            TAILB(s2)
            TAILB(s2 + 1)
            PREFQ(s2 + 2) PARTQ(s2 + 2)
            PREFQ(s2 + 3) PARTQ(s2 + 3)
            __syncthreads();
        }
#undef PREFQ
#undef PARTQ
#undef TAILB
    }
    __syncthreads();

    // ---- writeback, 4-way split ----
    #pragma unroll
    for (int w = 0; w < 4; ++w) {
        int idx = w * 256 + tid; int rr = idx >> 5, cc = idx & 31;
        gstore_cc(&R[(aI + rr) * NN + aJ + cc], Vtc[cc][rr]);
    }
    #pragma unroll
    for (int w = 0; w < 4; ++w) {
        int idx = w * 256 + tid; int cc = idx >> 5, rr = idx & 31;
        gstore_cc(&C[(aJ + cc) * NN + aI + rr], Vtc[cc][rr]);
    }
    VWAIT0;
    __syncthreads();
    if (tid == 0) gstore_flag(&flags[(I * TT + J) << 4], 1);
}

// ---------------------------------------------------------------------------
// Parallel traceback over independent split-segments (round-9, verified).
// ---------------------------------------------------------------------------
__global__ __launch_bounds__(256) void traceback_kernel(const double* __restrict__ R,
                                                        const double* __restrict__ C,
                                                        const float* __restrict__ S,
                                                        float* __restrict__ out,
                                                        int* __restrict__ qi,
                                                        int* __restrict__ qj,
                                                        int* __restrict__ qready,
                                                        int* __restrict__ qctl) {
    __shared__ double Rw[16][17];
    __shared__ float  Sw[16][17];
    __shared__ int sh_cmd, sh_i, sh_j;
    __shared__ double sred_v[4];
    __shared__ int sred_k[4];
    const double eps = 1e-9;
    const int tid = threadIdx.x;
    int* headp = qctl;
    int* tailp = qctl + 16;
    int* pendp = qctl + 32;

    int i = 0, j = 0; double v = 0.0;
    bool have = false;
    int ai = -(1 << 29), aj = 0;
    int myidx = -1;

    while (true) {
        if (tid == 0) {
            int cmd;
            int guard = 0;
            while (true) {
                if (!have) {
                    if (++guard > (1 << 22)) { cmd = -1; break; }   // watchdog
                    if (myidx < 0) myidx = atomicAdd(headp, 1);
                    int rdy = 0;
                    if (myidx < 4096)
                        rdy = __hip_atomic_load(&qready[myidx], __ATOMIC_RELAXED,
                                                __HIP_MEMORY_SCOPE_AGENT);
                    if (rdy) {
                        int ni, nj;
                        asm volatile("global_load_dword %0, %2, off sc0 sc1\n\t"
                                     "global_load_dword %1, %3, off sc0 sc1\n\t"
                                     "s_waitcnt vmcnt(0)"
                                     : "=&v"(ni), "=&v"(nj)
                                     : "v"(&qi[myidx]), "v"(&qj[myidx]));
                        myidx = -1;
                        i = ni; j = nj;
                        if (j <= i) { atomicAdd(pendp, -1); continue; }
                        v = R[i * NN + j];
                        if (v <= eps) { atomicAdd(pendp, -1); continue; }
                        have = true;
                        continue;
                    }
                    int pend = __hip_atomic_load(pendp, __ATOMIC_RELAXED,
                                                 __HIP_MEMORY_SCOPE_AGENT);
                    if (pend == 0) { cmd = -1; break; }
                    __builtin_amdgcn_s_sleep(2);
                    continue;
                }
                int u = i - ai, w = aj - j;
                if ((unsigned)u > 15u || (unsigned)w > 14u) { cmd = 1; break; }
                double a = Rw[u][w];                  // R[(i+1)*NN + j]
                if (a >= v - eps) {
                    ++i; v = a;
                    if (j <= i || v <= eps) { have = false; atomicAdd(pendp, -1); }
                    continue;
                }
                float sv = Sw[u][w];                  // S[i*NN + j]
                double b2 = Rw[u][w + 1];             // R[(i+1)*NN + j-1]
                if (sv > 0.0f && b2 + (double)sv >= v - eps) {
                    out[i * NN + j] = sv; out[j * NN + i] = sv;
                    ++i; --j; v = b2;
                    if (j <= i || v <= eps) { have = false; atomicAdd(pendp, -1); }
                    continue;
                }
                cmd = 0; break;                       // split
            }
            sh_cmd = cmd; sh_i = i; sh_j = j;
        }
        __syncthreads();
        int cmd = sh_cmd;
        if (cmd < 0) break;

        if (cmd == 1) {                               // refill window at (i,j)
            int i0 = sh_i, j0 = sh_j;
            int di = tid >> 4, dj = tid & 15;
            int rr = i0 + 1 + di; if (rr > NN - 1) rr = NN - 1;
            int cc = j0 - dj;     if (cc < 0) cc = 0;
            Rw[di][dj] = R[rr * NN + cc];
            int sr = i0 + di;     if (sr > NN - 1) sr = NN - 1;
            Sw[di][dj] = S[sr * NN + cc];
            __syncthreads();
            if (tid == 0) { ai = i0; aj = j0; }
            continue;
        }

        // cmd == 0: split via parallel argmax (first-max = smallest k)
        const int si = sh_i, sj = sh_j;
        double bv = -1.0; int bk = 0x7fffffff;
        for (int k = si + tid; k < sj; k += 256) {
            double tv = R[si * NN + k] + C[sj * NN + k + 1];
            if (tv > bv) { bv = tv; bk = k; }
        }
        for (int offr = 32; offr; offr >>= 1) {
            double ov = __shfl_down(bv, offr);
            int    ok = __shfl_down(bk, offr);
            if (ov > bv || (ov == bv && ok < bk)) { bv = ov; bk = ok; }
        }
        if ((tid & 63) == 0) { sred_v[tid >> 6] = bv; sred_k[tid >> 6] = bk; }
        __syncthreads();
        if (tid == 0) {
            double fv = sred_v[0]; int fk = sred_k[0];
            for (int w = 1; w < 4; ++w)
                if (sred_v[w] > fv || (sred_v[w] == fv && sred_k[w] < fk)) { fv = sred_v[w]; fk = sred_k[w]; }
            // push right child (fk+1, sj): data -> pending -> ready, ordered
            int slot = atomicAdd(tailp, 1);
            int rv = fk + 1;
            asm volatile("global_store_dword %0, %1, off sc0 sc1" :: "v"(&qi[slot]), "v"(rv));
            asm volatile("global_store_dword %0, %1, off sc0 sc1" :: "v"(&qj[slot]), "v"(sj));
            VWAIT0;                                   // qi/qj at MALL
            atomicAdd(pendp, 1);
            VWAIT0;                                   // pending+1 at MALL
            gstore_flag(&qready[slot], 1);
            // continue inline with left child (si, fk)
            j = fk;                                   // i == si already
            if (j <= i) { have = false; atomicAdd(pendp, -1); }
            else {
                v = R[i * NN + j];
                if (v <= eps) { have = false; atomicAdd(pendp, -1); }
                else have = true;
            }
        }
        __syncthreads();
    }
}

// ---------------------------------------------------------------------------
extern "C" void kernel_launch(void* const* d_in, const int* in_sizes, int n_in,
                              void* d_out, int out_size, void* d_ws, size_t ws_size,
                              hipStream_t stream) {
    const float* con  = (const float*)d_in[0];
    const float* feat = (const float*)d_in[1];
    float* out = (float*)d_out;

    char* ws = (char*)d_ws;
    double* R      = (double*)(ws);
    double* C      = (double*)(ws + (size_t)8  * 1024 * 1024);
    float*  S      = (float*) (ws + (size_t)16 * 1024 * 1024);
    int*    primes = (int*)   (ws + (size_t)20 * 1024 * 1024);
    int*    flags  = (int*)   (ws + (size_t)20 * 1024 * 1024 + 8192);
    char*   qbase  = ws + (size_t)20 * 1024 * 1024 + 128 * 1024;
    int*    qi     = (int*)(qbase);
    int*    qj     = (int*)(qbase + 16 * 1024);
    int*    qready = (int*)(qbase + 32 * 1024);
    int*    qctl   = (int*)(qbase + 48 * 1024);

    primes_kernel<<<(NN + 255) / 256, 256, 0, stream>>>(feat, primes);
    prep_kernel<<<(NN * NN) / 256, 256, 0, stream>>>(con, primes, S, R, C, out, flags,
                                                     qi, qj, qready, qctl);
    nuss_tiles_kernel<<<NTILES, 256, 0, stream>>>(R, C, S, flags);
    traceback_kernel<<<64, 256, 0, stream>>>(R, C, S, out, qi, qj, qready, qctl);
}

// Round 13
// 1141.178 us; speedup vs baseline: 1.0592x; 1.0592x over previous
//
#include <hip/hip_runtime.h>

#define NN 1024
#define BT 32
#define TT 32
#define NTILES ((TT * (TT + 1)) / 2)   // 528

// ---------------------------------------------------------------------------
// Fence-free cross-XCD protocol (batched sc0sc1 MALL ops). FINAL (= round-10,
// the session's verified best):
//  - tile DP: 4 waves/tile; phaseA k-tiles split by kk across waves; phaseB
//    4-wave k-split with in-step partials + 1 barrier/step (r11/r12 probes
//    in both neighboring directions measured worse -> local optimum)
//  - traceback: parallel split-segment work queue over 64 blocks (r9)
// ---------------------------------------------------------------------------
__device__ __forceinline__ double gload_cc(const double* p) {
    double v;
    asm volatile("global_load_dwordx2 %0, %1, off sc0 sc1" : "=v"(v) : "v"(p));
    return v;
}
__device__ __forceinline__ void gstore_cc(double* p, double v) {
    asm volatile("global_store_dwordx2 %0, %1, off sc0 sc1" :: "v"(p), "v"(v));
}
__device__ __forceinline__ void gstore_flag(int* p, int v) {
    asm volatile("global_store_dword %0, %1, off sc0 sc1" :: "v"(p), "v"(v));
}
#define VWAIT0 asm volatile("s_waitcnt vmcnt(0)" ::: "memory")

__device__ __forceinline__ void waitflag2(const int* f, int a0, int b0, int a1, int b1) {
    const int* p0 = &f[(a0 * TT + b0) << 4];
    const int* p1 = &f[(a1 * TT + b1) << 4];
    int it = 0;
    while (true) {
        int v0, v1;
        asm volatile("global_load_dword %0, %2, off sc0 sc1\n\t"
                     "global_load_dword %1, %3, off sc0 sc1\n\t"
                     "s_waitcnt vmcnt(0)"
                     : "=&v"(v0), "=&v"(v1)
                     : "v"(p0), "v"(p1));
        if (v0 & v1) break;
        if (it < 8) __builtin_amdgcn_s_sleep(1);
        else        __builtin_amdgcn_s_sleep(15);
        ++it;
    }
    asm volatile("" ::: "memory");
}
__device__ __forceinline__ void waitflag4(const int* f, int a0, int b0, int a1, int b1,
                                          int a2, int b2, int a3, int b3) {
    const int* p0 = &f[(a0 * TT + b0) << 4];
    const int* p1 = &f[(a1 * TT + b1) << 4];
    const int* p2 = &f[(a2 * TT + b2) << 4];
    const int* p3 = &f[(a3 * TT + b3) << 4];
    int it = 0;
    while (true) {
        int v0, v1, v2, v3;
        asm volatile("global_load_dword %0, %4, off sc0 sc1\n\t"
                     "global_load_dword %1, %5, off sc0 sc1\n\t"
                     "global_load_dword %2, %6, off sc0 sc1\n\t"
                     "global_load_dword %3, %7, off sc0 sc1\n\t"
                     "s_waitcnt vmcnt(0)"
                     : "=&v"(v0), "=&v"(v1), "=&v"(v2), "=&v"(v3)
                     : "v"(p0), "v"(p1), "v"(p2), "v"(p3));
        if (v0 & v1 & v2 & v3) break;
        if (it < 8) __builtin_amdgcn_s_sleep(1);
        else        __builtin_amdgcn_s_sleep(15);
        ++it;
    }
    asm volatile("" ::: "memory");
}
__device__ __forceinline__ void waitflag2_blk(const int* f, int a0, int b0, int a1, int b1) {
    if (threadIdx.x < 64) waitflag2(f, a0, b0, a1, b1);
    __syncthreads();
}
__device__ __forceinline__ void waitflag4_blk(const int* f, int a0, int b0, int a1, int b1,
                                              int a2, int b2, int a3, int b3) {
    if (threadIdx.x < 64) waitflag4(f, a0, b0, a1, b1, a2, b2, a3, b3);
    __syncthreads();
}

// ---------------------------------------------------------------------------
__global__ void primes_kernel(const float* __restrict__ feat, int* __restrict__ primes) {
    int i = blockIdx.x * blockDim.x + threadIdx.x;
    if (i < NN) {
        float best = feat[i * NN];
        int arg = 0;
        for (int ch = 1; ch < 4; ++ch) {
            float v = feat[ch * NN * NN + i * NN];
            if (v > best) { best = v; arg = ch; }
        }
        const int P[4] = {2, 3, 5, 7};
        primes[i] = P[arg];
    }
}

__global__ void prep_kernel(const float* __restrict__ con, const int* __restrict__ primes,
                            float* __restrict__ S, double* __restrict__ R,
                            double* __restrict__ C, float* __restrict__ out,
                            int* __restrict__ flags,
                            int* __restrict__ qi, int* __restrict__ qj,
                            int* __restrict__ qready, int* __restrict__ qctl) {
    int idx = blockIdx.x * blockDim.x + threadIdx.x;
    int i = idx >> 10;
    int j = idx & (NN - 1);
    float c = (con[idx] + con[j * NN + i]) * 0.5f;
    int prod = primes[i] * primes[j];
    bool canon = (prod == 14) | (prod == 15) | (prod == 35);
    int d = i - j; if (d < 0) d = -d;
    S[idx] = (canon && d >= 4) ? c : 0.0f;
    R[idx] = 0.0;
    C[idx] = 0.0;
    out[idx] = 0.0f;
    if (idx < TT * TT * 16) flags[idx] = 0;
    if (idx < 4096) qready[idx] = (idx == 0) ? 1 : 0;
    if (idx == 0) {
        qi[0] = 0; qj[0] = NN - 1;
        qctl[0] = 0;      // head
        qctl[16] = 1;     // tail
        qctl[32] = 1;     // pending
    }
}

// ---------------------------------------------------------------------------
// Dataflow DP, 4 waves per 32x32 tile. Exactness: every candidate is one
// fp64 add of stored values; extra candidates are dominated (-1e30+x<0<=dp,
// stale-0 + V(sub) <= dp by interval monotonicity); fmax is exact => bitwise
// == numpy. phaseB 4-wave split: term kk=r -> shfl(p1,2); kk=r+1 ->
// ar1+shfl(p2,4) with p2 shifted unconditionally; r==30 uses the static
// edge row, r==31 has no kk=r+1 term. Prefetched terms (kk>r+1, i.e. rows
// >=r+3) read LDS written >=1 barrier earlier.
// ---------------------------------------------------------------------------
__global__ __launch_bounds__(256) void nuss_tiles_kernel(double* __restrict__ R,
                                                         double* __restrict__ C,
                                                         const float* __restrict__ S,
                                                         int* __restrict__ flags) {
    __shared__ double DJJc[32][33];
    __shared__ double Vtc[32][33];
    __shared__ __attribute__((aligned(16))) double Ast[32][34];
    __shared__ __attribute__((aligned(16))) double Bst[32][34];
    __shared__ double Pld[32][33];
    __shared__ float  Sld[32][32];
    __shared__ double edgeCol[33];
    __shared__ double Prt[2][4][32];                 // per-step wave partials

    int b = blockIdx.x, dd = 0;
    while (b >= TT - dd) { b -= TT - dd; ++dd; }
    const int I = b, J = b + dd;
    const int aI = I * BT, aJ = J * BT;
    const int tid = threadIdx.x;
    const int wid = tid >> 6;
    const int lane = tid & 63;
    const int r = lane >> 1;
    const int h = lane & 1;

    if (dd == 0) {
        #pragma unroll
        for (int w = 0; w < 4; ++w) {
            int idx = w * 256 + tid; int rr = idx >> 5, cc = idx & 31;
            Sld[rr][cc] = S[(aI + rr) * NN + aI + cc];
        }
        for (int idx = tid; idx < 32 * 33; idx += 256)
            ((double*)Vtc)[idx] = 0.0;
        __syncthreads();
        if (wid == 0) {
            double vrow[16];
            #pragma unroll
            for (int u = 0; u < 16; ++u) vrow[u] = 0.0;
            for (int s = 1; s <= 31; ++s) {
                int c = r + s;
                bool act = (c <= 31);
                double acc = 0.0;
                if (act) {
                    double t0 = 0.0, t1 = 0.0, t2 = 0.0, t3 = 0.0;
                    #pragma unroll
                    for (int u = 0; u < 16; u += 4) {
                        int k0 = h * 16 + u;
                        t0 = fmax(t0, vrow[u]     + Vtc[c][k0 + 1]);
                        t1 = fmax(t1, vrow[u + 1] + Vtc[c][k0 + 2]);
                        t2 = fmax(t2, vrow[u + 2] + Vtc[c][k0 + 3]);
                        t3 = fmax(t3, vrow[u + 3] + Vtc[c][k0 + 4]);
                    }
                    acc = fmax(fmax(t0, t1), fmax(t2, t3));
                }
                acc = fmax(acc, __shfl_xor(acc, 1));
                if (act) {
                    double best = fmax(acc, Vtc[c - 1][r + 1] + (double)Sld[r][c]);
                    if (h == 0) Vtc[c][r] = best;
                    #pragma unroll
                    for (int u = 0; u < 16; ++u)
                        if (h * 16 + u == c) vrow[u] = best;
                }
            }
        }
        __syncthreads();
        #pragma unroll
        for (int w = 0; w < 4; ++w) {
            int idx = w * 256 + tid; int rr = idx >> 5, cc = idx & 31;
            gstore_cc(&R[(aI + rr) * NN + aI + cc], Vtc[cc][rr]);
        }
        #pragma unroll
        for (int w = 0; w < 4; ++w) {
            int idx = w * 256 + tid; int cc = idx >> 5, rr = idx & 31;
            gstore_cc(&C[(aI + cc) * NN + aI + rr], Vtc[cc][rr]);
        }
        VWAIT0;
        __syncthreads();
        if (tid == 0) gstore_flag(&flags[(I * TT + I) << 4], 1);
        return;
    }

    // ---------------- off-diagonal tile ----------------
    const int nk = dd - 1;
    const int off = (wid & 1) * 16 + h * 8;          // this lane's 8-term slice
    waitflag2_blk(flags, I, I, J, J);

    double ra[4], rb[4];
    double ec = 0.0, ve = 0.0;
    double asl[8];
    double ar1 = 0.0;
    #pragma unroll
    for (int w = 0; w < 4; ++w) {
        int idx = w * 256 + tid; int cc = idx >> 5, mm = idx & 31;
        ra[w] = gload_cc(&C[(aJ + cc) * NN + aJ + mm]);
    }
    if (wid < 2) {
        #pragma unroll
        for (int u = 0; u < 8; ++u)
            asl[u] = gload_cc(&R[(aI + r) * NN + aI + off + u]);
    }
    if (r < 31) ar1 = gload_cc(&R[(aI + r) * NN + aI + r + 1]);
    if (wid == 0 && nk == 0) {
        if (lane < 33) ec = gload_cc(&R[(aI + lane) * NN + (aJ - 1)]);
        if (lane < 32) ve = gload_cc(&R[(aI + 32) * NN + aJ + lane]);
    }
    #pragma unroll
    for (int w = 0; w < 4; ++w) {
        int idx = w * 256 + tid; int rr = idx >> 5, cc = idx & 31;
        Sld[rr][cc] = S[(aI + rr) * NN + aJ + cc];
    }
    for (int idx = tid; idx < 32 * 33; idx += 256)
        ((double*)Vtc)[idx] = 0.0;
    VWAIT0;
    #pragma unroll
    for (int w = 0; w < 4; ++w) {
        int idx = w * 256 + tid; int cc = idx >> 5, mm = idx & 31;
        DJJc[cc][mm] = ra[w];
    }
    if (tid < 32) DJJc[tid][32] = 0.0;
    // slice8: aslice (waves 0,1; guard kk>r+1) or vrow (waves 2,3; init 0)
    double slice8[8];
    if (wid < 2) {
        #pragma unroll
        for (int u = 0; u < 8; ++u)
            slice8[u] = (off + u > r + 1) ? asl[u] : -1.0e30;
    } else {
        #pragma unroll
        for (int u = 0; u < 8; ++u) slice8[u] = 0.0;
    }
    if (wid == 0 && nk == 0) {
        if (lane < 33) edgeCol[lane] = ec;
        if (lane < 32) Vtc[lane][32] = ve;
    }
    __syncthreads();

    // ---- phaseA: all-wave cooperative, middle-out, readiness pairs ----
    double P[16];
    #pragma unroll
    for (int x = 0; x < 16; ++x) P[x] = 0.0;
    const int rg = lane >> 3, cg = lane & 7;
    const int r4 = rg * 4, c4 = cg * 4;

    auto kkloop = [&]() {
        for (int kk = wid * 8; kk < wid * 8 + 8; ++kk) {
            double2 av0 = *(const double2*)&Ast[kk][r4];
            double2 av1 = *(const double2*)&Ast[kk][r4 + 2];
            double2 bv0 = *(const double2*)&Bst[kk][c4];
            double2 bv1 = *(const double2*)&Bst[kk][c4 + 2];
            P[0]  = fmax(P[0],  av0.x + bv0.x); P[1]  = fmax(P[1],  av0.x + bv0.y);
            P[2]  = fmax(P[2],  av0.x + bv1.x); P[3]  = fmax(P[3],  av0.x + bv1.y);
            P[4]  = fmax(P[4],  av0.y + bv0.x); P[5]  = fmax(P[5],  av0.y + bv0.y);
            P[6]  = fmax(P[6],  av0.y + bv1.x); P[7]  = fmax(P[7],  av0.y + bv1.y);
            P[8]  = fmax(P[8],  av1.x + bv0.x); P[9]  = fmax(P[9],  av1.x + bv0.y);
            P[10] = fmax(P[10], av1.x + bv1.x); P[11] = fmax(P[11], av1.x + bv1.y);
            P[12] = fmax(P[12], av1.y + bv0.x); P[13] = fmax(P[13], av1.y + bv0.y);
            P[14] = fmax(P[14], av1.y + bv1.x); P[15] = fmax(P[15], av1.y + bv1.y);
        }
    };
    auto proc = [&](int t1, int t2, bool last) {
        if (t2 >= 0) waitflag4_blk(flags, I, t1, t1, J, I, t2, t2, J);
        else         waitflag2_blk(flags, I, t1, t1, J);
        if (last && wid == 0) {
            if (lane < 33) ec = gload_cc(&R[(aI + lane) * NN + (aJ - 1)]);
            if (lane < 32) ve = gload_cc(&R[(aI + 32) * NN + aJ + lane]);
        }
        int k1 = t1 * BT;
        #pragma unroll
        for (int w = 0; w < 4; ++w) {
            int idx = w * 256 + tid; int rr = idx >> 5, kk = idx & 31;
            ra[w] = gload_cc(&R[(aI + rr) * NN + k1 + kk]);
            rb[w] = gload_cc(&C[(aJ + rr) * NN + k1 + 1 + kk]);
        }
        VWAIT0;
        #pragma unroll
        for (int w = 0; w < 4; ++w) {
            int idx = w * 256 + tid; int rr = idx >> 5, kk = idx & 31;
            Ast[kk][rr] = ra[w];
            Bst[kk][rr] = rb[w];
        }
        if (last && wid == 0) {
            if (lane < 33) edgeCol[lane] = ec;
            if (lane < 32) Vtc[lane][32] = ve;
        }
        __syncthreads();
        if (t2 >= 0) {
            int k2 = t2 * BT;
            #pragma unroll
            for (int w = 0; w < 4; ++w) {
                int idx = w * 256 + tid; int rr = idx >> 5, kk = idx & 31;
                ra[w] = gload_cc(&R[(aI + rr) * NN + k2 + kk]);
                rb[w] = gload_cc(&C[(aJ + rr) * NN + k2 + 1 + kk]);
            }
        }
        kkloop();
        if (t2 >= 0) {
            __syncthreads();
            VWAIT0;
            #pragma unroll
            for (int w = 0; w < 4; ++w) {
                int idx = w * 256 + tid; int rr = idx >> 5, kk = idx & 31;
                Ast[kk][rr] = ra[w];
                Bst[kk][rr] = rb[w];
            }
            __syncthreads();
            kkloop();
        }
        __syncthreads();
    };

    {
        int tl = (I + J) >> 1, tr = ((I + J) >> 1) + 1;
        int pend = -1;
        for (int q = 0; q < nk; ++q) {
            int t;
            if ((q & 1) == 0) { if (tl >= I + 1) t = tl--; else t = tr++; }
            else              { if (tr <= J - 1) t = tr++; else t = tl--; }
            if (pend < 0) { pend = t; continue; }
            int rp = (pend - I > J - pend) ? pend - I : J - pend;
            int rt = (t - I > J - t) ? t - I : J - t;
            if (rp == rt) { proc(pend, t, q == nk - 1); pend = -1; }
            else          { proc(pend, -1, false); pend = t; }
        }
        if (pend >= 0) proc(pend, -1, true);
    }

    // ---- Pld merge (exact fmax, fixed barrier order) ----
    if (nk > 0) {
        if (wid == 0) {
            #pragma unroll
            for (int x = 0; x < 4; ++x)
                #pragma unroll
                for (int y = 0; y < 4; ++y)
                    Pld[r4 + x][c4 + y] = P[x * 4 + y];
        }
        __syncthreads();
        if (wid == 1) {
            #pragma unroll
            for (int x = 0; x < 4; ++x)
                #pragma unroll
                for (int y = 0; y < 4; ++y)
                    Pld[r4 + x][c4 + y] = fmax(Pld[r4 + x][c4 + y], P[x * 4 + y]);
        }
        __syncthreads();
        if (wid == 2) {
            #pragma unroll
            for (int x = 0; x < 4; ++x)
                #pragma unroll
                for (int y = 0; y < 4; ++y)
                    Pld[r4 + x][c4 + y] = fmax(Pld[r4 + x][c4 + y], P[x * 4 + y]);
        }
        __syncthreads();
        if (wid == 3) {
            #pragma unroll
            for (int x = 0; x < 4; ++x)
                #pragma unroll
                for (int y = 0; y < 4; ++y)
                    Pld[r4 + x][c4 + y] = fmax(Pld[r4 + x][c4 + y], P[x * 4 + y]);
        }
        __syncthreads();
    } else {
        for (int idx = tid; idx < 32 * 33; idx += 256)
            ((double*)Pld)[idx] = 0.0;
        __syncthreads();
    }

    // ---- phaseB: 4-wave k-split, 1 barrier/step, redundant tail ----
    {
        const double* bsel = (wid < 2) ? &Vtc[0][0] : &DJJc[0][0];
        double ecr = edgeCol[r];
        double ecp = edgeCol[r + 1];
        double pA[8], pB[8];
        double p1 = 0.0, p2 = 0.0, shc = 0.0, shp = 0.0, erc = 0.0, erp = 0.0;

#define PREFQ(PV, SS)                                                 \
    { int cq_ = (r + (SS) - 31) & 31;                                 \
      const double* bp_ = bsel + cq_ * 33 + off + 1;                  \
      _Pragma("unroll")                                               \
      for (int u = 0; u < 8; ++u) PV[u] = bp_[u]; }

#define STEPQ(PV, SS, BUF)                                            \
    { int c_ = r + (SS) - 31;                                         \
      bool act_ = ((unsigned)c_ < 32u);                               \
      int cc_ = c_ & 31;                                              \
      double t0_ = fmax(slice8[0] + PV[0], slice8[1] + PV[1]);        \
      double t1_ = fmax(slice8[2] + PV[2], slice8[3] + PV[3]);        \
      double t2_ = fmax(slice8[4] + PV[4], slice8[5] + PV[5]);        \
      double t3_ = fmax(slice8[6] + PV[6], slice8[7] + PV[7]);        \
      double pa_ = fmax(fmax(t0_, t1_), fmax(t2_, t3_));              \
      pa_ = fmax(pa_, __shfl_xor(pa_, 1));                            \
      if (h == 0) Prt[BUF][wid][r] = pa_;                             \
      __syncthreads();                                                \
      double a0_ = Prt[BUF][0][r];                                    \
      double a1_ = Prt[BUF][1][r];                                    \
      double a2_ = Prt[BUF][2][r];                                    \
      double a3_ = Prt[BUF][3][r];                                    \
      double er_  = Vtc[cc_][32];                                     \
      double dj0_ = DJJc[cc_][0];                                     \
      double pld_ = Pld[r][cc_];                                      \
      float  sld_ = Sld[r][cc_];                                      \
      shp = shc; erp = erc; erc = er_;                                \
      shc = __shfl_down(p1, 2);                                       \
      double shd_ = __shfl_down(p2, 4);                               \
      p2 = p1;                                                        \
      double acc_ = fmax(fmax(a0_, a1_), fmax(a2_, a3_));             \
      if (act_) {                                                     \
          double best_ = acc_;                                        \
          best_ = fmax(best_, (r == 31) ? erc : shc);                 \
          if (r < 31)                                                 \
              best_ = fmax(best_, ar1 + ((r == 30) ? erc : shd_));    \
          best_ = fmax(best_, ecr + dj0_);                            \
          best_ = fmax(best_, pld_);                                  \
          double pv_ = (c_ == 0) ? ecp : ((r == 31) ? erp : shp);     \
          best_ = fmax(best_, pv_ + (double)sld_);                    \
          if (wid == 0 && h == 0) Vtc[c_][r] = best_;                 \
          if (wid >= 2) {                                             \
              _Pragma("unroll")                                       \
              for (int u = 0; u < 8; ++u)                             \
                  if (off + u == c_) slice8[u] = best_;               \
          }                                                           \
          p1 = best_;                                                 \
      } }

        PREFQ(pA, 0)
        PREFQ(pB, 1)
        for (int s2 = 0; s2 < 64; s2 += 2) {
            STEPQ(pA, s2, 0)
            PREFQ(pA, s2 + 2)
            STEPQ(pB, s2 + 1, 1)
            PREFQ(pB, s2 + 3)
        }
#undef PREFQ
#undef STEPQ
    }
    __syncthreads();

    // ---- writeback, 4-way split ----
    #pragma unroll
    for (int w = 0; w < 4; ++w) {
        int idx = w * 256 + tid; int rr = idx >> 5, cc = idx & 31;
        gstore_cc(&R[(aI + rr) * NN + aJ + cc], Vtc[cc][rr]);
    }
    #pragma unroll
    for (int w = 0; w < 4; ++w) {
        int idx = w * 256 + tid; int cc = idx >> 5, rr = idx & 31;
        gstore_cc(&C[(aJ + cc) * NN + aI + rr], Vtc[cc][rr]);
    }
    VWAIT0;
    __syncthreads();
    if (tid == 0) gstore_flag(&flags[(I * TT + J) << 4], 1);
}

// ---------------------------------------------------------------------------
// Parallel traceback over independent split-segments (round-9, verified).
// ---------------------------------------------------------------------------
__global__ __launch_bounds__(256) void traceback_kernel(const double* __restrict__ R,
                                                        const double* __restrict__ C,
                                                        const float* __restrict__ S,
                                                        float* __restrict__ out,
                                                        int* __restrict__ qi,
                                                        int* __restrict__ qj,
                                                        int* __restrict__ qready,
                                                        int* __restrict__ qctl) {
    __shared__ double Rw[16][17];
    __shared__ float  Sw[16][17];
    __shared__ int sh_cmd, sh_i, sh_j;
    __shared__ double sred_v[4];
    __shared__ int sred_k[4];
    const double eps = 1e-9;
    const int tid = threadIdx.x;
    int* headp = qctl;
    int* tailp = qctl + 16;
    int* pendp = qctl + 32;

    int i = 0, j = 0; double v = 0.0;
    bool have = false;
    int ai = -(1 << 29), aj = 0;
    int myidx = -1;

    while (true) {
        if (tid == 0) {
            int cmd;
            int guard = 0;
            while (true) {
                if (!have) {
                    if (++guard > (1 << 22)) { cmd = -1; break; }   // watchdog
                    if (myidx < 0) myidx = atomicAdd(headp, 1);
                    int rdy = 0;
                    if (myidx < 4096)
                        rdy = __hip_atomic_load(&qready[myidx], __ATOMIC_RELAXED,
                                                __HIP_MEMORY_SCOPE_AGENT);
                    if (rdy) {
                        int ni, nj;
                        asm volatile("global_load_dword %0, %2, off sc0 sc1\n\t"
                                     "global_load_dword %1, %3, off sc0 sc1\n\t"
                                     "s_waitcnt vmcnt(0)"
                                     : "=&v"(ni), "=&v"(nj)
                                     : "v"(&qi[myidx]), "v"(&qj[myidx]));
                        myidx = -1;
                        i = ni; j = nj;
                        if (j <= i) { atomicAdd(pendp, -1); continue; }
                        v = R[i * NN + j];
                        if (v <= eps) { atomicAdd(pendp, -1); continue; }
                        have = true;
                        continue;
                    }
                    int pend = __hip_atomic_load(pendp, __ATOMIC_RELAXED,
                                                 __HIP_MEMORY_SCOPE_AGENT);
                    if (pend == 0) { cmd = -1; break; }
                    __builtin_amdgcn_s_sleep(2);
                    continue;
                }
                int u = i - ai, w = aj - j;
                if ((unsigned)u > 15u || (unsigned)w > 14u) { cmd = 1; break; }
                double a = Rw[u][w];                  // R[(i+1)*NN + j]
                if (a >= v - eps) {
                    ++i; v = a;
                    if (j <= i || v <= eps) { have = false; atomicAdd(pendp, -1); }
                    continue;
                }
                float sv = Sw[u][w];                  // S[i*NN + j]
                double b2 = Rw[u][w + 1];             // R[(i+1)*NN + j-1]
                if (sv > 0.0f && b2 + (double)sv >= v - eps) {
                    out[i * NN + j] = sv; out[j * NN + i] = sv;
                    ++i; --j; v = b2;
                    if (j <= i || v <= eps) { have = false; atomicAdd(pendp, -1); }
                    continue;
                }
                cmd = 0; break;                       // split
            }
            sh_cmd = cmd; sh_i = i; sh_j = j;
        }
        __syncthreads();
        int cmd = sh_cmd;
        if (cmd < 0) break;

        if (cmd == 1) {                               // refill window at (i,j)
            int i0 = sh_i, j0 = sh_j;
            int di = tid >> 4, dj = tid & 15;
            int rr = i0 + 1 + di; if (rr > NN - 1) rr = NN - 1;
            int cc = j0 - dj;     if (cc < 0) cc = 0;
            Rw[di][dj] = R[rr * NN + cc];
            int sr = i0 + di;     if (sr > NN - 1) sr = NN - 1;
            Sw[di][dj] = S[sr * NN + cc];
            __syncthreads();
            if (tid == 0) { ai = i0; aj = j0; }
            continue;
        }

        // cmd == 0: split via parallel argmax (first-max = smallest k)
        const int si = sh_i, sj = sh_j;
        double bv = -1.0; int bk = 0x7fffffff;
        for (int k = si + tid; k < sj; k += 256) {
            double tv = R[si * NN + k] + C[sj * NN + k + 1];
            if (tv > bv) { bv = tv; bk = k; }
        }
        for (int offr = 32; offr; offr >>= 1) {
            double ov = __shfl_down(bv, offr);
            int    ok = __shfl_down(bk, offr);
            if (ov > bv || (ov == bv && ok < bk)) { bv = ov; bk = ok; }
        }
        if ((tid & 63) == 0) { sred_v[tid >> 6] = bv; sred_k[tid >> 6] = bk; }
        __syncthreads();
        if (tid == 0) {
            double fv = sred_v[0]; int fk = sred_k[0];
            for (int w = 1; w < 4; ++w)
                if (sred_v[w] > fv || (sred_v[w] == fv && sred_k[w] < fk)) { fv = sred_v[w]; fk = sred_k[w]; }
            // push right child (fk+1, sj): data -> pending -> ready, ordered
            int slot = atomicAdd(tailp, 1);
            int rv = fk + 1;
            asm volatile("global_store_dword %0, %1, off sc0 sc1" :: "v"(&qi[slot]), "v"(rv));
            asm volatile("global_store_dword %0, %1, off sc0 sc1" :: "v"(&qj[slot]), "v"(sj));
            VWAIT0;                                   // qi/qj at MALL
            atomicAdd(pendp, 1);
            VWAIT0;                                   // pending+1 at MALL
            gstore_flag(&qready[slot], 1);
            // continue inline with left child (si, fk)
            j = fk;                                   // i == si already
            if (j <= i) { have = false; atomicAdd(pendp, -1); }
            else {
                v = R[i * NN + j];
                if (v <= eps) { have = false; atomicAdd(pendp, -1); }
                else have = true;
            }
        }
        __syncthreads();
    }
}

// ---------------------------------------------------------------------------
extern "C" void kernel_launch(void* const* d_in, const int* in_sizes, int n_in,
                              void* d_out, int out_size, void* d_ws, size_t ws_size,
                              hipStream_t stream) {
    const float* con  = (const float*)d_in[0];
    const float* feat = (const float*)d_in[1];
    float* out = (float*)d_out;

    char* ws = (char*)d_ws;
    double* R      = (double*)(ws);
    double* C      = (double*)(ws + (size_t)8  * 1024 * 1024);
    float*  S      = (float*) (ws + (size_t)16 * 1024 * 1024);
    int*    primes = (int*)   (ws + (size_t)20 * 1024 * 1024);
    int*    flags  = (int*)   (ws + (size_t)20 * 1024 * 1024 + 8192);
    char*   qbase  = ws + (size_t)20 * 1024 * 1024 + 128 * 1024;
    int*    qi     = (int*)(qbase);
    int*    qj     = (int*)(qbase + 16 * 1024);
    int*    qready = (int*)(qbase + 32 * 1024);
    int*    qctl   = (int*)(qbase + 48 * 1024);

    primes_kernel<<<(NN + 255) / 256, 256, 0, stream>>>(feat, primes);
    prep_kernel<<<(NN * NN) / 256, 256, 0, stream>>>(con, primes, S, R, C, out, flags,
                                                     qi, qj, qready, qctl);
    nuss_tiles_kernel<<<NTILES, 256, 0, stream>>>(R, C, S, flags);
    traceback_kernel<<<64, 256, 0, stream>>>(R, C, S, out, qi, qj, qready, qctl);
}

// Round 14
// 1129.847 us; speedup vs baseline: 1.0699x; 1.0100x over previous
//
#include <hip/hip_runtime.h>

#define NN 1024
#define BT 32
#define TT 32
#define NTILES ((TT * (TT + 1)) / 2)   // 528
#define TBBLK 64                        // traceback blocks appended to the grid

// ---------------------------------------------------------------------------
// Fence-free cross-XCD protocol (batched sc0sc1 MALL ops). Round-14:
// = round-10/13 verified-best DP + r9 parallel traceback, FUSED into one
// dispatch. Traceback blocks (blockIdx >= NTILES) gate on flag (0,31)
// (transitively implies every tile done), then run the r9 queue walk with
// LDS overlaid on the nuss arrays (footprint unchanged -> 3 blocks/CU).
// Normal cached loads in traceback are safe: dispatch-start acquire
// invalidated L2; R/C are sc0sc1-only during the DP, so first normal read
// fetches final data from MALL and values never change afterwards.
// prep: R/C zeroing vectorized to double2.
// ---------------------------------------------------------------------------
__device__ __forceinline__ double gload_cc(const double* p) {
    double v;
    asm volatile("global_load_dwordx2 %0, %1, off sc0 sc1" : "=v"(v) : "v"(p));
    return v;
}
__device__ __forceinline__ void gstore_cc(double* p, double v) {
    asm volatile("global_store_dwordx2 %0, %1, off sc0 sc1" :: "v"(p), "v"(v));
}
__device__ __forceinline__ void gstore_flag(int* p, int v) {
    asm volatile("global_store_dword %0, %1, off sc0 sc1" :: "v"(p), "v"(v));
}
#define VWAIT0 asm volatile("s_waitcnt vmcnt(0)" ::: "memory")

__device__ __forceinline__ void waitflag2(const int* f, int a0, int b0, int a1, int b1) {
    const int* p0 = &f[(a0 * TT + b0) << 4];
    const int* p1 = &f[(a1 * TT + b1) << 4];
    int it = 0;
    while (true) {
        int v0, v1;
        asm volatile("global_load_dword %0, %2, off sc0 sc1\n\t"
                     "global_load_dword %1, %3, off sc0 sc1\n\t"
                     "s_waitcnt vmcnt(0)"
                     : "=&v"(v0), "=&v"(v1)
                     : "v"(p0), "v"(p1));
        if (v0 & v1) break;
        if (it < 8) __builtin_amdgcn_s_sleep(1);
        else        __builtin_amdgcn_s_sleep(15);
        ++it;
    }
    asm volatile("" ::: "memory");
}
__device__ __forceinline__ void waitflag4(const int* f, int a0, int b0, int a1, int b1,
                                          int a2, int b2, int a3, int b3) {
    const int* p0 = &f[(a0 * TT + b0) << 4];
    const int* p1 = &f[(a1 * TT + b1) << 4];
    const int* p2 = &f[(a2 * TT + b2) << 4];
    const int* p3 = &f[(a3 * TT + b3) << 4];
    int it = 0;
    while (true) {
        int v0, v1, v2, v3;
        asm volatile("global_load_dword %0, %4, off sc0 sc1\n\t"
                     "global_load_dword %1, %5, off sc0 sc1\n\t"
                     "global_load_dword %2, %6, off sc0 sc1\n\t"
                     "global_load_dword %3, %7, off sc0 sc1\n\t"
                     "s_waitcnt vmcnt(0)"
                     : "=&v"(v0), "=&v"(v1), "=&v"(v2), "=&v"(v3)
                     : "v"(p0), "v"(p1), "v"(p2), "v"(p3));
        if (v0 & v1 & v2 & v3) break;
        if (it < 8) __builtin_amdgcn_s_sleep(1);
        else        __builtin_amdgcn_s_sleep(15);
        ++it;
    }
    asm volatile("" ::: "memory");
}
__device__ __forceinline__ void waitflag2_blk(const int* f, int a0, int b0, int a1, int b1) {
    if (threadIdx.x < 64) waitflag2(f, a0, b0, a1, b1);
    __syncthreads();
}
__device__ __forceinline__ void waitflag4_blk(const int* f, int a0, int b0, int a1, int b1,
                                              int a2, int b2, int a3, int b3) {
    if (threadIdx.x < 64) waitflag4(f, a0, b0, a1, b1, a2, b2, a3, b3);
    __syncthreads();
}

// ---------------------------------------------------------------------------
__global__ void primes_kernel(const float* __restrict__ feat, int* __restrict__ primes) {
    int i = blockIdx.x * blockDim.x + threadIdx.x;
    if (i < NN) {
        float best = feat[i * NN];
        int arg = 0;
        for (int ch = 1; ch < 4; ++ch) {
            float v = feat[ch * NN * NN + i * NN];
            if (v > best) { best = v; arg = ch; }
        }
        const int P[4] = {2, 3, 5, 7};
        primes[i] = P[arg];
    }
}

__global__ void prep_kernel(const float* __restrict__ con, const int* __restrict__ primes,
                            float* __restrict__ S, double* __restrict__ R,
                            double* __restrict__ C, float* __restrict__ out,
                            int* __restrict__ flags,
                            int* __restrict__ qi, int* __restrict__ qj,
                            int* __restrict__ qready, int* __restrict__ qctl) {
    int idx = blockIdx.x * blockDim.x + threadIdx.x;
    int i = idx >> 10;
    int j = idx & (NN - 1);
    float c = (con[idx] + con[j * NN + i]) * 0.5f;
    int prod = primes[i] * primes[j];
    bool canon = (prod == 14) | (prod == 15) | (prod == 35);
    int d = i - j; if (d < 0) d = -d;
    S[idx] = (canon && d >= 4) ? c : 0.0f;
    out[idx] = 0.0f;
    if (idx < NN * NN / 2) {                         // double2-vectorized zeroing
        ((double2*)R)[idx] = make_double2(0.0, 0.0);
        ((double2*)C)[idx] = make_double2(0.0, 0.0);
    }
    if (idx < TT * TT * 16) flags[idx] = 0;
    if (idx < 4096) qready[idx] = (idx == 0) ? 1 : 0;
    if (idx == 0) {
        qi[0] = 0; qj[0] = NN - 1;
        qctl[0] = 0;      // head
        qctl[16] = 1;     // tail
        qctl[32] = 1;     // pending
    }
}

// ---------------------------------------------------------------------------
// Fused kernel: blocks < NTILES = dataflow tile DP (round-10 verified body);
// blocks >= NTILES = parallel traceback (round-9 verified body, LDS overlay).
// ---------------------------------------------------------------------------
__global__ __launch_bounds__(256) void nuss_fused_kernel(double* __restrict__ R,
                                                         double* __restrict__ C,
                                                         const float* __restrict__ S,
                                                         int* __restrict__ flags,
                                                         float* __restrict__ out,
                                                         int* __restrict__ qi,
                                                         int* __restrict__ qj,
                                                         int* __restrict__ qready,
                                                         int* __restrict__ qctl) {
    __shared__ double DJJc[32][33];
    __shared__ double Vtc[32][33];
    __shared__ __attribute__((aligned(16))) double Ast[32][34];
    __shared__ __attribute__((aligned(16))) double Bst[32][34];
    __shared__ double Pld[32][33];
    __shared__ float  Sld[32][32];
    __shared__ double edgeCol[33];
    __shared__ double Prt[2][4][32];                 // per-step wave partials

    const int tid = threadIdx.x;
    const int wid = tid >> 6;
    const int lane = tid & 63;

    if (blockIdx.x >= NTILES) {
        // ================= traceback branch (r9 body, LDS overlay) =========
        double (*Rw)[17] = (double(*)[17])&DJJc[0][0];   // 16x17 doubles
        float  (*Sw)[17] = (float (*)[17])&Vtc[0][0];    // 16x17 floats
        int*    shctl    = (int*)&Pld[0][0];             // [0]=cmd [1]=i [2]=j
        double* sredv    = &Pld[2][0];                   // 4 doubles
        int*    sredk    = (int*)&Pld[4][0];             // 4 ints
        const double eps = 1e-9;
        int* headp = qctl;
        int* tailp = qctl + 16;
        int* pendp = qctl + 32;

        // Gate: flag (0,31) transitively implies ALL tiles complete.
        if (tid == 0) {
            const int* fr = &flags[(0 * TT + 31) << 4];
            int it = 0;
            while (true) {
                int v0;
                asm volatile("global_load_dword %0, %1, off sc0 sc1\n\t"
                             "s_waitcnt vmcnt(0)" : "=&v"(v0) : "v"(fr));
                if (v0) break;
                if (it < 8) __builtin_amdgcn_s_sleep(1);
                else        __builtin_amdgcn_s_sleep(15);
                ++it;
            }
            asm volatile("" ::: "memory");
        }
        __syncthreads();

        int i = 0, j = 0; double v = 0.0;
        bool have = false;
        int ai = -(1 << 29), aj = 0;
        int myidx = -1;

        while (true) {
            if (tid == 0) {
                int cmd;
                int guard = 0;
                while (true) {
                    if (!have) {
                        if (++guard > (1 << 22)) { cmd = -1; break; }   // watchdog
                        if (myidx < 0) myidx = atomicAdd(headp, 1);
                        int rdy = 0;
                        if (myidx < 4096)
                            rdy = __hip_atomic_load(&qready[myidx], __ATOMIC_RELAXED,
                                                    __HIP_MEMORY_SCOPE_AGENT);
                        if (rdy) {
                            int ni, nj;
                            asm volatile("global_load_dword %0, %2, off sc0 sc1\n\t"
                                         "global_load_dword %1, %3, off sc0 sc1\n\t"
                                         "s_waitcnt vmcnt(0)"
                                         : "=&v"(ni), "=&v"(nj)
                                         : "v"(&qi[myidx]), "v"(&qj[myidx]));
                            myidx = -1;
                            i = ni; j = nj;
                            if (j <= i) { atomicAdd(pendp, -1); continue; }
                            v = R[i * NN + j];
                            if (v <= eps) { atomicAdd(pendp, -1); continue; }
                            have = true;
                            continue;
                        }
                        int pend = __hip_atomic_load(pendp, __ATOMIC_RELAXED,
                                                     __HIP_MEMORY_SCOPE_AGENT);
                        if (pend == 0) { cmd = -1; break; }
                        __builtin_amdgcn_s_sleep(2);
                        continue;
                    }
                    int u = i - ai, w = aj - j;
                    if ((unsigned)u > 15u || (unsigned)w > 14u) { cmd = 1; break; }
                    double a = Rw[u][w];                  // R[(i+1)*NN + j]
                    if (a >= v - eps) {
                        ++i; v = a;
                        if (j <= i || v <= eps) { have = false; atomicAdd(pendp, -1); }
                        continue;
                    }
                    float sv = Sw[u][w];                  // S[i*NN + j]
                    double b2 = Rw[u][w + 1];             // R[(i+1)*NN + j-1]
                    if (sv > 0.0f && b2 + (double)sv >= v - eps) {
                        out[i * NN + j] = sv; out[j * NN + i] = sv;
                        ++i; --j; v = b2;
                        if (j <= i || v <= eps) { have = false; atomicAdd(pendp, -1); }
                        continue;
                    }
                    cmd = 0; break;                       // split
                }
                shctl[0] = cmd; shctl[1] = i; shctl[2] = j;
            }
            __syncthreads();
            int cmd = shctl[0];
            if (cmd < 0) break;

            if (cmd == 1) {                               // refill window at (i,j)
                int i0 = shctl[1], j0 = shctl[2];
                int di = tid >> 4, dj = tid & 15;
                int rr = i0 + 1 + di; if (rr > NN - 1) rr = NN - 1;
                int cc = j0 - dj;     if (cc < 0) cc = 0;
                Rw[di][dj] = R[rr * NN + cc];
                int sr = i0 + di;     if (sr > NN - 1) sr = NN - 1;
                Sw[di][dj] = S[sr * NN + cc];
                __syncthreads();
                if (tid == 0) { ai = i0; aj = j0; }
                continue;
            }

            // cmd == 0: split via parallel argmax (first-max = smallest k)
            const int si = shctl[1], sj = shctl[2];
            double bv = -1.0; int bk = 0x7fffffff;
            for (int k = si + tid; k < sj; k += 256) {
                double tv = R[si * NN + k] + C[sj * NN + k + 1];
                if (tv > bv) { bv = tv; bk = k; }
            }
            for (int offr = 32; offr; offr >>= 1) {
                double ov = __shfl_down(bv, offr);
                int    ok = __shfl_down(bk, offr);
                if (ov > bv || (ov == bv && ok < bk)) { bv = ov; bk = ok; }
            }
            if ((tid & 63) == 0) { sredv[tid >> 6] = bv; sredk[tid >> 6] = bk; }
            __syncthreads();
            if (tid == 0) {
                double fv = sredv[0]; int fk = sredk[0];
                for (int w = 1; w < 4; ++w)
                    if (sredv[w] > fv || (sredv[w] == fv && sredk[w] < fk)) { fv = sredv[w]; fk = sredk[w]; }
                // push right child (fk+1, sj): data -> pending -> ready, ordered
                int slot = atomicAdd(tailp, 1);
                int rv = fk + 1;
                asm volatile("global_store_dword %0, %1, off sc0 sc1" :: "v"(&qi[slot]), "v"(rv));
                asm volatile("global_store_dword %0, %1, off sc0 sc1" :: "v"(&qj[slot]), "v"(sj));
                VWAIT0;                                   // qi/qj at MALL
                atomicAdd(pendp, 1);
                VWAIT0;                                   // pending+1 at MALL
                gstore_flag(&qready[slot], 1);
                // continue inline with left child (si, fk)
                j = fk;                                   // i == si already
                if (j <= i) { have = false; atomicAdd(pendp, -1); }
                else {
                    v = R[i * NN + j];
                    if (v <= eps) { have = false; atomicAdd(pendp, -1); }
                    else have = true;
                }
            }
            __syncthreads();
        }
        return;
    }

    // ===================== tile-DP branch (round-10 body) ===================
    int b = blockIdx.x, dd = 0;
    while (b >= TT - dd) { b -= TT - dd; ++dd; }
    const int I = b, J = b + dd;
    const int aI = I * BT, aJ = J * BT;
    const int r = lane >> 1;
    const int h = lane & 1;

    if (dd == 0) {
        #pragma unroll
        for (int w = 0; w < 4; ++w) {
            int idx = w * 256 + tid; int rr = idx >> 5, cc = idx & 31;
            Sld[rr][cc] = S[(aI + rr) * NN + aI + cc];
        }
        for (int idx = tid; idx < 32 * 33; idx += 256)
            ((double*)Vtc)[idx] = 0.0;
        __syncthreads();
        if (wid == 0) {
            double vrow[16];
            #pragma unroll
            for (int u = 0; u < 16; ++u) vrow[u] = 0.0;
            for (int s = 1; s <= 31; ++s) {
                int c = r + s;
                bool act = (c <= 31);
                double acc = 0.0;
                if (act) {
                    double t0 = 0.0, t1 = 0.0, t2 = 0.0, t3 = 0.0;
                    #pragma unroll
                    for (int u = 0; u < 16; u += 4) {
                        int k0 = h * 16 + u;
                        t0 = fmax(t0, vrow[u]     + Vtc[c][k0 + 1]);
                        t1 = fmax(t1, vrow[u + 1] + Vtc[c][k0 + 2]);
                        t2 = fmax(t2, vrow[u + 2] + Vtc[c][k0 + 3]);
                        t3 = fmax(t3, vrow[u + 3] + Vtc[c][k0 + 4]);
                    }
                    acc = fmax(fmax(t0, t1), fmax(t2, t3));
                }
                acc = fmax(acc, __shfl_xor(acc, 1));
                if (act) {
                    double best = fmax(acc, Vtc[c - 1][r + 1] + (double)Sld[r][c]);
                    if (h == 0) Vtc[c][r] = best;
                    #pragma unroll
                    for (int u = 0; u < 16; ++u)
                        if (h * 16 + u == c) vrow[u] = best;
                }
            }
        }
        __syncthreads();
        #pragma unroll
        for (int w = 0; w < 4; ++w) {
            int idx = w * 256 + tid; int rr = idx >> 5, cc = idx & 31;
            gstore_cc(&R[(aI + rr) * NN + aI + cc], Vtc[cc][rr]);
        }
        #pragma unroll
        for (int w = 0; w < 4; ++w) {
            int idx = w * 256 + tid; int cc = idx >> 5, rr = idx & 31;
            gstore_cc(&C[(aI + cc) * NN + aI + rr], Vtc[cc][rr]);
        }
        VWAIT0;
        __syncthreads();
        if (tid == 0) gstore_flag(&flags[(I * TT + I) << 4], 1);
        return;
    }

    // ---------------- off-diagonal tile ----------------
    const int nk = dd - 1;
    const int off = (wid & 1) * 16 + h * 8;          // this lane's 8-term slice
    waitflag2_blk(flags, I, I, J, J);

    double ra[4], rb[4];
    double ec = 0.0, ve = 0.0;
    double asl[8];
    double ar1 = 0.0;
    #pragma unroll
    for (int w = 0; w < 4; ++w) {
        int idx = w * 256 + tid; int cc = idx >> 5, mm = idx & 31;
        ra[w] = gload_cc(&C[(aJ + cc) * NN + aJ + mm]);
    }
    if (wid < 2) {
        #pragma unroll
        for (int u = 0; u < 8; ++u)
            asl[u] = gload_cc(&R[(aI + r) * NN + aI + off + u]);
    }
    if (r < 31) ar1 = gload_cc(&R[(aI + r) * NN + aI + r + 1]);
    if (wid == 0 && nk == 0) {
        if (lane < 33) ec = gload_cc(&R[(aI + lane) * NN + (aJ - 1)]);
        if (lane < 32) ve = gload_cc(&R[(aI + 32) * NN + aJ + lane]);
    }
    #pragma unroll
    for (int w = 0; w < 4; ++w) {
        int idx = w * 256 + tid; int rr = idx >> 5, cc = idx & 31;
        Sld[rr][cc] = S[(aI + rr) * NN + aJ + cc];
    }
    for (int idx = tid; idx < 32 * 33; idx += 256)
        ((double*)Vtc)[idx] = 0.0;
    VWAIT0;
    #pragma unroll
    for (int w = 0; w < 4; ++w) {
        int idx = w * 256 + tid; int cc = idx >> 5, mm = idx & 31;
        DJJc[cc][mm] = ra[w];
    }
    if (tid < 32) DJJc[tid][32] = 0.0;
    // slice8: aslice (waves 0,1; guard kk>r+1) or vrow (waves 2,3; init 0)
    double slice8[8];
    if (wid < 2) {
        #pragma unroll
        for (int u = 0; u < 8; ++u)
            slice8[u] = (off + u > r + 1) ? asl[u] : -1.0e30;
    } else {
        #pragma unroll
        for (int u = 0; u < 8; ++u) slice8[u] = 0.0;
    }
    if (wid == 0 && nk == 0) {
        if (lane < 33) edgeCol[lane] = ec;
        if (lane < 32) Vtc[lane][32] = ve;
    }
    __syncthreads();

    // ---- phaseA: all-wave cooperative, middle-out, readiness pairs ----
    double P[16];
    #pragma unroll
    for (int x = 0; x < 16; ++x) P[x] = 0.0;
    const int rg = lane >> 3, cg = lane & 7;
    const int r4 = rg * 4, c4 = cg * 4;

    auto kkloop = [&]() {
        for (int kk = wid * 8; kk < wid * 8 + 8; ++kk) {
            double2 av0 = *(const double2*)&Ast[kk][r4];
            double2 av1 = *(const double2*)&Ast[kk][r4 + 2];
            double2 bv0 = *(const double2*)&Bst[kk][c4];
            double2 bv1 = *(const double2*)&Bst[kk][c4 + 2];
            P[0]  = fmax(P[0],  av0.x + bv0.x); P[1]  = fmax(P[1],  av0.x + bv0.y);
            P[2]  = fmax(P[2],  av0.x + bv1.x); P[3]  = fmax(P[3],  av0.x + bv1.y);
            P[4]  = fmax(P[4],  av0.y + bv0.x); P[5]  = fmax(P[5],  av0.y + bv0.y);
            P[6]  = fmax(P[6],  av0.y + bv1.x); P[7]  = fmax(P[7],  av0.y + bv1.y);
            P[8]  = fmax(P[8],  av1.x + bv0.x); P[9]  = fmax(P[9],  av1.x + bv0.y);
            P[10] = fmax(P[10], av1.x + bv1.x); P[11] = fmax(P[11], av1.x + bv1.y);
            P[12] = fmax(P[12], av1.y + bv0.x); P[13] = fmax(P[13], av1.y + bv0.y);
            P[14] = fmax(P[14], av1.y + bv1.x); P[15] = fmax(P[15], av1.y + bv1.y);
        }
    };
    auto proc = [&](int t1, int t2, bool last) {
        if (t2 >= 0) waitflag4_blk(flags, I, t1, t1, J, I, t2, t2, J);
        else         waitflag2_blk(flags, I, t1, t1, J);
        if (last && wid == 0) {
            if (lane < 33) ec = gload_cc(&R[(aI + lane) * NN + (aJ - 1)]);
            if (lane < 32) ve = gload_cc(&R[(aI + 32) * NN + aJ + lane]);
        }
        int k1 = t1 * BT;
        #pragma unroll
        for (int w = 0; w < 4; ++w) {
            int idx = w * 256 + tid; int rr = idx >> 5, kk = idx & 31;
            ra[w] = gload_cc(&R[(aI + rr) * NN + k1 + kk]);
            rb[w] = gload_cc(&C[(aJ + rr) * NN + k1 + 1 + kk]);
        }
        VWAIT0;
        #pragma unroll
        for (int w = 0; w < 4; ++w) {
            int idx = w * 256 + tid; int rr = idx >> 5, kk = idx & 31;
            Ast[kk][rr] = ra[w];
            Bst[kk][rr] = rb[w];
        }
        if (last && wid == 0) {
            if (lane < 33) edgeCol[lane] = ec;
            if (lane < 32) Vtc[lane][32] = ve;
        }
        __syncthreads();
        if (t2 >= 0) {
            int k2 = t2 * BT;
            #pragma unroll
            for (int w = 0; w < 4; ++w) {
                int idx = w * 256 + tid; int rr = idx >> 5, kk = idx & 31;
                ra[w] = gload_cc(&R[(aI + rr) * NN + k2 + kk]);
                rb[w] = gload_cc(&C[(aJ + rr) * NN + k2 + 1 + kk]);
            }
        }
        kkloop();
        if (t2 >= 0) {
            __syncthreads();
            VWAIT0;
            #pragma unroll
            for (int w = 0; w < 4; ++w) {
                int idx = w * 256 + tid; int rr = idx >> 5, kk = idx & 31;
                Ast[kk][rr] = ra[w];
                Bst[kk][rr] = rb[w];
            }
            __syncthreads();
            kkloop();
        }
        __syncthreads();
    };

    {
        int tl = (I + J) >> 1, tr = ((I + J) >> 1) + 1;
        int pend = -1;
        for (int q = 0; q < nk; ++q) {
            int t;
            if ((q & 1) == 0) { if (tl >= I + 1) t = tl--; else t = tr++; }
            else              { if (tr <= J - 1) t = tr++; else t = tl--; }
            if (pend < 0) { pend = t; continue; }
            int rp = (pend - I > J - pend) ? pend - I : J - pend;
            int rt = (t - I > J - t) ? t - I : J - t;
            if (rp == rt) { proc(pend, t, q == nk - 1); pend = -1; }
            else          { proc(pend, -1, false); pend = t; }
        }
        if (pend >= 0) proc(pend, -1, true);
    }

    // ---- Pld merge (exact fmax, fixed barrier order) ----
    if (nk > 0) {
        if (wid == 0) {
            #pragma unroll
            for (int x = 0; x < 4; ++x)
                #pragma unroll
                for (int y = 0; y < 4; ++y)
                    Pld[r4 + x][c4 + y] = P[x * 4 + y];
        }
        __syncthreads();
        if (wid == 1) {
            #pragma unroll
            for (int x = 0; x < 4; ++x)
                #pragma unroll
                for (int y = 0; y < 4; ++y)
                    Pld[r4 + x][c4 + y] = fmax(Pld[r4 + x][c4 + y], P[x * 4 + y]);
        }
        __syncthreads();
        if (wid == 2) {
            #pragma unroll
            for (int x = 0; x < 4; ++x)
                #pragma unroll
                for (int y = 0; y < 4; ++y)
                    Pld[r4 + x][c4 + y] = fmax(Pld[r4 + x][c4 + y], P[x * 4 + y]);
        }
        __syncthreads();
        if (wid == 3) {
            #pragma unroll
            for (int x = 0; x < 4; ++x)
                #pragma unroll
                for (int y = 0; y < 4; ++y)
                    Pld[r4 + x][c4 + y] = fmax(Pld[r4 + x][c4 + y], P[x * 4 + y]);
        }
        __syncthreads();
    } else {
        for (int idx = tid; idx < 32 * 33; idx += 256)
            ((double*)Pld)[idx] = 0.0;
        __syncthreads();
    }

    // ---- phaseB: 4-wave k-split, 1 barrier/step, redundant tail ----
    {
        const double* bsel = (wid < 2) ? &Vtc[0][0] : &DJJc[0][0];
        double ecr = edgeCol[r];
        double ecp = edgeCol[r + 1];
        double pA[8], pB[8];
        double p1 = 0.0, p2 = 0.0, shc = 0.0, shp = 0.0, erc = 0.0, erp = 0.0;

#define PREFQ(PV, SS)                                                 \
    { int cq_ = (r + (SS) - 31) & 31;                                 \
      const double* bp_ = bsel + cq_ * 33 + off + 1;                  \
      _Pragma("unroll")                                               \
      for (int u = 0; u < 8; ++u) PV[u] = bp_[u]; }

#define STEPQ(PV, SS, BUF)                                            \
    { int c_ = r + (SS) - 31;                                         \
      bool act_ = ((unsigned)c_ < 32u);                               \
      int cc_ = c_ & 31;                                              \
      double t0_ = fmax(slice8[0] + PV[0], slice8[1] + PV[1]);        \
      double t1_ = fmax(slice8[2] + PV[2], slice8[3] + PV[3]);        \
      double t2_ = fmax(slice8[4] + PV[4], slice8[5] + PV[5]);        \
      double t3_ = fmax(slice8[6] + PV[6], slice8[7] + PV[7]);        \
      double pa_ = fmax(fmax(t0_, t1_), fmax(t2_, t3_));              \
      pa_ = fmax(pa_, __shfl_xor(pa_, 1));                            \
      if (h == 0) Prt[BUF][wid][r] = pa_;                             \
      __syncthreads();                                                \
      double a0_ = Prt[BUF][0][r];                                    \
      double a1_ = Prt[BUF][1][r];                                    \
      double a2_ = Prt[BUF][2][r];                                    \
      double a3_ = Prt[BUF][3][r];                                    \
      double er_  = Vtc[cc_][32];                                     \
      double dj0_ = DJJc[cc_][0];                                     \
      double pld_ = Pld[r][cc_];                                      \
      float  sld_ = Sld[r][cc_];                                      \
      shp = shc; erp = erc; erc = er_;                                \
      shc = __shfl_down(p1, 2);                                       \
      double shd_ = __shfl_down(p2, 4);                               \
      p2 = p1;                                                        \
      double acc_ = fmax(fmax(a0_, a1_), fmax(a2_, a3_));             \
      if (act_) {                                                     \
          double best_ = acc_;                                        \
          best_ = fmax(best_, (r == 31) ? erc : shc);                 \
          if (r < 31)                                                 \
              best_ = fmax(best_, ar1 + ((r == 30) ? erc : shd_));    \
          best_ = fmax(best_, ecr + dj0_);                            \
          best_ = fmax(best_, pld_);                                  \
          double pv_ = (c_ == 0) ? ecp : ((r == 31) ? erp : shp);     \
          best_ = fmax(best_, pv_ + (double)sld_);                    \
          if (wid == 0 && h == 0) Vtc[c_][r] = best_;                 \
          if (wid >= 2) {                                             \
              _Pragma("unroll")                                       \
              for (int u = 0; u < 8; ++u)                             \
                  if (off + u == c_) slice8[u] = best_;               \
          }                                                           \
          p1 = best_;                                                 \
      } }

        PREFQ(pA, 0)
        PREFQ(pB, 1)
        for (int s2 = 0; s2 < 64; s2 += 2) {
            STEPQ(pA, s2, 0)
            PREFQ(pA, s2 + 2)
            STEPQ(pB, s2 + 1, 1)
            PREFQ(pB, s2 + 3)
        }
#undef PREFQ
#undef STEPQ
    }
    __syncthreads();

    // ---- writeback, 4-way split ----
    #pragma unroll
    for (int w = 0; w < 4; ++w) {
        int idx = w * 256 + tid; int rr = idx >> 5, cc = idx & 31;
        gstore_cc(&R[(aI + rr) * NN + aJ + cc], Vtc[cc][rr]);
    }
    #pragma unroll
    for (int w = 0; w < 4; ++w) {
        int idx = w * 256 + tid; int cc = idx >> 5, rr = idx & 31;
        gstore_cc(&C[(aJ + cc) * NN + aI + rr], Vtc[cc][rr]);
    }
    VWAIT0;
    __syncthreads();
    if (tid == 0) gstore_flag(&flags[(I * TT + J) << 4], 1);
}

// ---------------------------------------------------------------------------
extern "C" void kernel_launch(void* const* d_in, const int* in_sizes, int n_in,
                              void* d_out, int out_size, void* d_ws, size_t ws_size,
                              hipStream_t stream) {
    const float* con  = (const float*)d_in[0];
    const float* feat = (const float*)d_in[1];
    float* out = (float*)d_out;

    char* ws = (char*)d_ws;
    double* R      = (double*)(ws);
    double* C      = (double*)(ws + (size_t)8  * 1024 * 1024);
    float*  S      = (float*) (ws + (size_t)16 * 1024 * 1024);
    int*    primes = (int*)   (ws + (size_t)20 * 1024 * 1024);
    int*    flags  = (int*)   (ws + (size_t)20 * 1024 * 1024 + 8192);
    char*   qbase  = ws + (size_t)20 * 1024 * 1024 + 128 * 1024;
    int*    qi     = (int*)(qbase);
    int*    qj     = (int*)(qbase + 16 * 1024);
    int*    qready = (int*)(qbase + 32 * 1024);
    int*    qctl   = (int*)(qbase + 48 * 1024);

    primes_kernel<<<(NN + 255) / 256, 256, 0, stream>>>(feat, primes);
    prep_kernel<<<(NN * NN) / 256, 256, 0, stream>>>(con, primes, S, R, C, out, flags,
                                                     qi, qj, qready, qctl);
    nuss_fused_kernel<<<NTILES + TBBLK, 256, 0, stream>>>(R, C, S, flags, out,
                                                          qi, qj, qready, qctl);
}